// Round 1
// baseline (179.206 us; speedup 1.0000x reference)
//
#include <hip/hip_runtime.h>
#include <stdint.h>

// ODE sampler (VP-SDE probability-flow, RK4, T=50) for B=2048, D=16, H=256.
// tr(J) analytic: tr = -0.5*beta*(D + sum_k (1-h_k^2)*c_k).
//
// R7: latency-bound at grid-capped 2 waves/SIMD (real VALU issue ~34%; the
// 71% VALUBusy is the gfx94x SIMD-16 formula, 2x-inflated on CDNA4 SIMD-32).
// Shorten the per-Feval dependency chain and trim uniform work:
//  - v_cvt_pkrtz (1 instr) for all hot f32->f16x2 packs (bcast, h-store).
//  - fdot2 chains split 8-deep -> 2x4-deep + add tree (both phases).
//  - u-init (b1+t*wt) hoisted per t-value (tm shared by k2/k3, t1 -> next
//    t0); beta/nhb/wb per step; b2 prescaled by 1/8 folded into accumulator
//    init (kills post-DPP adds); sum(wb) is a constexpr (WBSUM); trace is
//    sum(h^2*ck) with the sum(ck) term folded into one final fma.
//  - phase-2 b128 reads issued right after the h write; trace block sits in
//    their latency shadow.
// Carried from R6: SGPR x-broadcast via readlane, DPP-only score reduce,
// conflict-free CH=20 h layout, prescale by 2*log2(e) for tanh via exp2.

typedef _Float16 f16x2 __attribute__((ext_vector_type(2)));

#if defined(__has_builtin)
#if __has_builtin(__builtin_amdgcn_fdot2)
#define HAVE_FDOT2 1
#endif
#endif

__device__ __forceinline__ float fdot2f(f16x2 a, f16x2 b, float c) {
#ifdef HAVE_FDOT2
    return __builtin_amdgcn_fdot2(a, b, c, false);
#else
    return fmaf((float)a.y, (float)b.y, fmaf((float)a.x, (float)b.x, c));
#endif
}

// init path: RNE packing (accuracy for weights)
__device__ __forceinline__ uint32_t pk_rne(float a, float b) {
    f16x2 v; v.x = (_Float16)a; v.y = (_Float16)b;
    return __builtin_bit_cast(uint32_t, v);
}
// hot path: single-instruction pack (v_cvt_pkrtz_f16_f32)
__device__ __forceinline__ uint32_t pkz(float a, float b) {
    auto v = __builtin_amdgcn_cvt_pkrtz(a, b);
    return __builtin_bit_cast(uint32_t, v);
}
__device__ __forceinline__ f16x2 upk(uint32_t u) {
    return __builtin_bit_cast(f16x2, u);
}

// DPP add: x + x_from(lane permuted by ctrl); VALU pipe, no DS.
#define DPP_XOR1 0xB1    // quad_perm [1,0,3,2]
#define DPP_XOR2 0x4E    // quad_perm [2,3,0,1]
#define DPP_RHM  0x141   // row_half_mirror (xor-7 within 8-lane half-row)
template <int CTRL>
__device__ __forceinline__ float dpp_add(float x) {
    int v = __builtin_amdgcn_update_dpp(
        0, __builtin_bit_cast(int, x), CTRL, 0xF, 0xF, true);
    return x + __builtin_bit_cast(float, v);
}

#define Bn 2048
#define Dn 16
#define Hn 256
#define Tn 50
#define CH 20            // dwords per 32-k h chunk: 16 data + 4 pad

constexpr float T_LO = 1e-3f;
constexpr float DTc  = (1.0f - 1e-3f) / (float)(Tn - 1);
constexpr float W1W  = DTc * (1.f / 6.f);
constexpr float W2W  = DTc * (2.f / 6.f);

constexpr float nh_c(float t) { return -0.5f * (0.1f + 19.9f * t); }
constexpr float wbsum_c() {
    float s = 0.f;
    for (int j = 0; j < Tn - 1; ++j) {
        float t0 = T_LO + (float)j * DTc;
        float tm = t0 + 0.5f * DTc;
        float t1 = t0 + DTc;
        s += W1W * nh_c(t0) + 2.f * W2W * nh_c(tm) + W1W * nh_c(t1);
    }
    return s;
}
constexpr float WBSUM = wbsum_c();   // sum of RK-weighted (-beta/2) factors

__global__ __launch_bounds__(64) void ode_kernel(
    const float* __restrict__ x_in,   // [B][D]
    const float* __restrict__ W1,     // [D][H]
    const float* __restrict__ b1v,    // [H]
    const float* __restrict__ wtv,    // [H]
    const float* __restrict__ W2,     // [H][D]
    const float* __restrict__ b2v,    // [D]
    float* __restrict__ out)          // xf[B*D] | ldjf[B] | xt[T*B*D]
{
    __shared__ __align__(16) uint32_t h_lds[8 * CH];  // h, f16-pair packed

    const int L  = threadIdx.x;       // one wave per block = one sample
    const int g8 = L >> 3;            // i-pair group 0..7
    const int c  = L & 7;             // phase-2 k-chunk (32 k's)
    const int ia = 2 * g8, ib = ia + 1;
    const int k0 = 4 * L;             // phase-1: this lane's 4 hidden units
    const int gs = blockIdx.x;

    const float K2 = 2.88539008f;     // 2*log2(e): u' = K2*u, exp2(u') = e^{2u}

    // ---- one-time init: weights packed to f16 registers ----
    f16x2 w1p[4][8];                  // prescaled: {K2*W1[2j][k0+q], K2*W1[2j+1][k0+q]}
    float b1k[4], wtk[4], ck[4];
    #pragma unroll
    for (int q = 0; q < 4; ++q) {
        const int k = k0 + q;
        #pragma unroll
        for (int j = 0; j < 8; ++j) {
            f16x2 v;
            v.x = (_Float16)(K2 * W1[(2 * j)     * Hn + k]);
            v.y = (_Float16)(K2 * W1[(2 * j + 1) * Hn + k]);
            w1p[q][j] = v;
        }
        b1k[q] = K2 * b1v[k];
        wtk[q] = K2 * wtv[k];
        float s = 0.f;                // ck from ORIGINAL f32 weights
        #pragma unroll
        for (int ii = 0; ii < 16; ++ii)
            s = fmaf(W1[ii * Hn + k], W2[k * Dn + ii], s);
        ck[q] = s;
    }
    const float cksum = (ck[0] + ck[1]) + (ck[2] + ck[3]);

    f16x2 w2a[16], w2b[16];           // [m] = {W2[32c+2m][i*], W2[32c+2m+1][i*]}
    #pragma unroll
    for (int m = 0; m < 16; ++m) {
        f16x2 va, vb;
        va.x = (_Float16)W2[(32 * c + 2 * m)     * Dn + ia];
        va.y = (_Float16)W2[(32 * c + 2 * m + 1) * Dn + ia];
        vb.x = (_Float16)W2[(32 * c + 2 * m)     * Dn + ib];
        vb.y = (_Float16)W2[(32 * c + 2 * m + 1) * Dn + ib];
        w2a[m] = va; w2b[m] = vb;
    }
    const float b2a8 = 0.125f * b2v[ia];   // b2 / 8: folded into accumulator
    const float b2b8 = 0.125f * b2v[ib];   // init, restored by the 8-lane sum

    float xa = x_in[gs * Dn + ia];
    float xb = x_in[gs * Dn + ib];
    float ldjl = 0.f;                 // per-lane ldj partial (-sum wb*h^2ck)

    float* xf_out  = out;
    float* ldj_out = out + (size_t)Bn * Dn;
    float* xt_ptr  = out + (size_t)Bn * Dn + Bn + gs * Dn + ia;

    if (c == 0) *(float2*)xt_ptr = make_float2(xa, xb);   // xt[0]
    xt_ptr += Bn * Dn;

    const int hwidx = CH * (L >> 3) + 2 * (L & 7);        // h write slot (b64)

    // eval-point broadcast registers (uniform -> SGPRs)
    uint32_t se0, se1, se2, se3, se4, se5, se6, se7;
    auto bcast = [&](float ea, float eb) {
        const uint32_t vpk = pkz(ea, eb);     // every lane packs ITS pair
        se0 = __builtin_amdgcn_readlane(vpk,  0);
        se1 = __builtin_amdgcn_readlane(vpk,  8);
        se2 = __builtin_amdgcn_readlane(vpk, 16);
        se3 = __builtin_amdgcn_readlane(vpk, 24);
        se4 = __builtin_amdgcn_readlane(vpk, 32);
        se5 = __builtin_amdgcn_readlane(vpk, 40);
        se6 = __builtin_amdgcn_readlane(vpk, 48);
        se7 = __builtin_amdgcn_readlane(vpk, 56);
    };

    auto Feval = [&](float xeva, float xevb, const float (&ui)[4],
                     float nhb, float wb, float& dxa, float& dxb) {
        // ---- phase 1: this lane's 4 hidden units (SGPR-broadcast x) ----
        const f16x2 xp[8] = { upk(se0), upk(se1), upk(se2), upk(se3),
                              upk(se4), upk(se5), upk(se6), upk(se7) };
        float u0 = ui[0], u1 = ui[1], u2 = ui[2], u3 = ui[3];
        float v0 = 0.f, v1 = 0.f, v2 = 0.f, v3 = 0.f;
        #pragma unroll
        for (int j = 0; j < 4; ++j) {
            u0 = fdot2f(xp[j], w1p[0][j], u0);
            u1 = fdot2f(xp[j], w1p[1][j], u1);
            u2 = fdot2f(xp[j], w1p[2][j], u2);
            u3 = fdot2f(xp[j], w1p[3][j], u3);
        }
        #pragma unroll
        for (int j = 4; j < 8; ++j) {
            v0 = fdot2f(xp[j], w1p[0][j], v0);
            v1 = fdot2f(xp[j], w1p[1][j], v1);
            v2 = fdot2f(xp[j], w1p[2][j], v2);
            v3 = fdot2f(xp[j], w1p[3][j], v3);
        }
        u0 += v0; u1 += v1; u2 += v2; u3 += v3;
        // u is prescaled: exp2(u) = e^{2u_true}. tanh = 1 - 2/(E+1);
        // E->inf => h=1, E->0 => h=-1: saturation correct, no clamp.
        const float h0 = fmaf(-2.f, __builtin_amdgcn_rcpf(__builtin_amdgcn_exp2f(u0) + 1.f), 1.f);
        const float h1 = fmaf(-2.f, __builtin_amdgcn_rcpf(__builtin_amdgcn_exp2f(u1) + 1.f), 1.f);
        const float h2 = fmaf(-2.f, __builtin_amdgcn_rcpf(__builtin_amdgcn_exp2f(u2) + 1.f), 1.f);
        const float h3 = fmaf(-2.f, __builtin_amdgcn_rcpf(__builtin_amdgcn_exp2f(u3) + 1.f), 1.f);
        *(uint2*)&h_lds[hwidx] = make_uint2(pkz(h0, h1), pkz(h2, h3));

        asm volatile("" ::: "memory");     // keep h write above the reads

        // issue all 4 b128 reads immediately; trace fills their latency
        const uint4 hv0 = *(const uint4*)&h_lds[CH * c +  0];
        const uint4 hv1 = *(const uint4*)&h_lds[CH * c +  4];
        const uint4 hv2 = *(const uint4*)&h_lds[CH * c +  8];
        const uint4 hv3 = *(const uint4*)&h_lds[CH * c + 12];

        // trace partial: ldjl -= wb * sum(h^2 * ck); sum(ck) folded at end
        const float q0 = h0 * h0, q1 = h1 * h1, q2 = h2 * h2, q3 = h3 * h3;
        const float sq = fmaf(q0, ck[0], fmaf(q1, ck[1], fmaf(q2, ck[2], q3 * ck[3])));
        ldjl = fmaf(-wb, sq, ldjl);

        // ---- phase 2: score for (ia, ib) over k-chunk c (2x4-deep chains) ----
        float sa0 = b2a8, sa1 = 0.f, sb0 = b2b8, sb1 = 0.f;
        float ta0 = 0.f,  ta1 = 0.f, tb0 = 0.f,  tb1 = 0.f;
        {
            const f16x2 p0 = upk(hv0.x), p1 = upk(hv0.y), p2 = upk(hv0.z), p3 = upk(hv0.w);
            sa0 = fdot2f(p0, w2a[0], sa0);  sb0 = fdot2f(p0, w2b[0], sb0);
            sa1 = fdot2f(p1, w2a[1], sa1);  sb1 = fdot2f(p1, w2b[1], sb1);
            sa0 = fdot2f(p2, w2a[2], sa0);  sb0 = fdot2f(p2, w2b[2], sb0);
            sa1 = fdot2f(p3, w2a[3], sa1);  sb1 = fdot2f(p3, w2b[3], sb1);
        }
        {
            const f16x2 p0 = upk(hv1.x), p1 = upk(hv1.y), p2 = upk(hv1.z), p3 = upk(hv1.w);
            sa0 = fdot2f(p0, w2a[4], sa0);  sb0 = fdot2f(p0, w2b[4], sb0);
            sa1 = fdot2f(p1, w2a[5], sa1);  sb1 = fdot2f(p1, w2b[5], sb1);
            sa0 = fdot2f(p2, w2a[6], sa0);  sb0 = fdot2f(p2, w2b[6], sb0);
            sa1 = fdot2f(p3, w2a[7], sa1);  sb1 = fdot2f(p3, w2b[7], sb1);
        }
        {
            const f16x2 p0 = upk(hv2.x), p1 = upk(hv2.y), p2 = upk(hv2.z), p3 = upk(hv2.w);
            ta0 = fdot2f(p0, w2a[ 8], ta0);  tb0 = fdot2f(p0, w2b[ 8], tb0);
            ta1 = fdot2f(p1, w2a[ 9], ta1);  tb1 = fdot2f(p1, w2b[ 9], tb1);
            ta0 = fdot2f(p2, w2a[10], ta0);  tb0 = fdot2f(p2, w2b[10], tb0);
            ta1 = fdot2f(p3, w2a[11], ta1);  tb1 = fdot2f(p3, w2b[11], tb1);
        }
        {
            const f16x2 p0 = upk(hv3.x), p1 = upk(hv3.y), p2 = upk(hv3.z), p3 = upk(hv3.w);
            ta0 = fdot2f(p0, w2a[12], ta0);  tb0 = fdot2f(p0, w2b[12], tb0);
            ta1 = fdot2f(p1, w2a[13], ta1);  tb1 = fdot2f(p1, w2b[13], tb1);
            ta0 = fdot2f(p2, w2a[14], ta0);  tb0 = fdot2f(p2, w2b[14], tb0);
            ta1 = fdot2f(p3, w2a[15], ta1);  tb1 = fdot2f(p3, w2b[15], tb1);
        }
        float sca = (sa0 + sa1) + (ta0 + ta1);
        float scb = (sb0 + sb1) + (tb0 + tb1);
        // 8-lane reduce on the VALU pipe (DPP), no DS ops:
        sca = dpp_add<DPP_XOR1>(sca);  scb = dpp_add<DPP_XOR1>(scb);
        sca = dpp_add<DPP_XOR2>(sca);  scb = dpp_add<DPP_XOR2>(scb);
        sca = dpp_add<DPP_RHM >(sca);  scb = dpp_add<DPP_RHM >(scb);

        dxa = nhb * (xeva + sca);
        dxb = nhb * (xevb + scb);
    };

    // per-t-value uniforms, hoisted off the Feval critical path
    float ui0[4], uim[4], uit[4];
    #pragma unroll
    for (int q = 0; q < 4; ++q) ui0[q] = fmaf(T_LO, wtk[q], b1k[q]);
    float nhb0 = -0.5f * fmaf(T_LO, 19.9f, 0.1f);

    bcast(xa, xb);
    for (int j = 0; j < Tn - 1; ++j) {
        const float t0 = fmaf((float)j, DTc, T_LO);
        const float tm = t0 + 0.5f * DTc;
        const float t1 = t0 + DTc;
        #pragma unroll
        for (int q = 0; q < 4; ++q) {
            uim[q] = fmaf(tm, wtk[q], b1k[q]);
            uit[q] = fmaf(t1, wtk[q], b1k[q]);
        }
        const float nhbm = -0.5f * fmaf(tm, 19.9f, 0.1f);
        const float nhb1 = -0.5f * fmaf(t1, 19.9f, 0.1f);
        const float wb0 = W1W * nhb0;
        const float wbm = W2W * nhbm;      // shared by k2 and k3
        const float wb1 = W1W * nhb1;

        float k1a, k1b, k2a, k2b, k3a, k3b, k4a, k4b;

        Feval(xa, xb, ui0, nhb0, wb0, k1a, k1b);
        const float e2a = fmaf(0.5f * DTc, k1a, xa);
        const float e2b = fmaf(0.5f * DTc, k1b, xb);
        bcast(e2a, e2b);
        Feval(e2a, e2b, uim, nhbm, wbm, k2a, k2b);
        const float e3a = fmaf(0.5f * DTc, k2a, xa);
        const float e3b = fmaf(0.5f * DTc, k2b, xb);
        bcast(e3a, e3b);
        Feval(e3a, e3b, uim, nhbm, wbm, k3a, k3b);
        const float e4a = fmaf(DTc, k3a, xa);
        const float e4b = fmaf(DTc, k3b, xb);
        bcast(e4a, e4b);
        Feval(e4a, e4b, uit, nhb1, wb1, k4a, k4b);

        xa = fmaf(W1W, k1a + 2.f * (k2a + k3a) + k4a, xa);
        xb = fmaf(W1W, k1b + 2.f * (k2b + k3b) + k4b, xb);
        if (c == 0) *(float2*)xt_ptr = make_float2(xa, xb);
        xt_ptr += Bn * Dn;
        bcast(xa, xb);

        #pragma unroll
        for (int q = 0; q < 4; ++q) ui0[q] = uit[q];   // t1 -> next t0
        nhb0 = nhb1;
    }

    if (c == 0) *(float2*)(xf_out + gs * Dn + ia) = make_float2(xa, xb);

    // ldj: fold the constant (D/64 + sum ck) * sum(wb) term, then butterfly
    ldjl = fmaf(cksum + 0.25f, WBSUM, ldjl);
    #pragma unroll
    for (int off = 1; off < 64; off <<= 1)
        ldjl += __shfl_xor(ldjl, off);
    if (L == 0) ldj_out[gs] = ldjl;
}

extern "C" void kernel_launch(void* const* d_in, const int* in_sizes, int n_in,
                              void* d_out, int out_size, void* d_ws, size_t ws_size,
                              hipStream_t stream) {
    const float* x  = (const float*)d_in[0];
    const float* W1 = (const float*)d_in[1];
    const float* b1 = (const float*)d_in[2];
    const float* wt = (const float*)d_in[3];
    const float* W2 = (const float*)d_in[4];
    const float* b2 = (const float*)d_in[5];
    (void)in_sizes; (void)n_in; (void)out_size; (void)d_ws; (void)ws_size;
    ode_kernel<<<Bn, 64, 0, stream>>>(x, W1, b1, wt, W2, b2, (float*)d_out);
}

// Round 2
// 171.283 us; speedup vs baseline: 1.0463x; 1.0463x over previous
//
#include <hip/hip_runtime.h>
#include <stdint.h>

// ODE sampler (VP-SDE probability-flow, RK4, T=50) for B=2048, D=16, H=256.
// tr(J) analytic: tr = -0.5*beta*(D + sum_k (1-h_k^2)*c_k).
//
// R8: un-bundle R7. R7's post-mortem: duration tracks VALU instruction
// count (~75% VALU-pipe occupancy; only ~25% stall), so chain-depth
// splitting (extra accumulators + merge adds) REGRESSED while the
// instruction-count cuts were wins. This version = R6 structure (8-deep
// fdot2 chains, per-mq interleaved LDS reads) + R7's verified reductions:
//  - v_cvt_pkrtz (1 instr) for all hot f32->f16x2 packs (bcast, h-store).
//  - u-init (b1+t*wt) hoisted per t-value (tm shared by k2/k3, t1 -> next
//    t0); beta/nhb/wb hoisted per step.
//  - b2/8 folded into phase-2 accumulator init (kills post-DPP adds).
//  - sum(wb) is a constexpr (WBSUM); trace is sum(h^2*ck), the constant
//    (D/64 + sum ck)*WBSUM term folded into one final fma.
// Carried from R6: SGPR x-broadcast via readlane, DPP-only score reduce,
// conflict-free CH=20 h layout, prescale by 2*log2(e) for tanh via exp2.

typedef _Float16 f16x2 __attribute__((ext_vector_type(2)));

#if defined(__has_builtin)
#if __has_builtin(__builtin_amdgcn_fdot2)
#define HAVE_FDOT2 1
#endif
#endif

__device__ __forceinline__ float fdot2f(f16x2 a, f16x2 b, float c) {
#ifdef HAVE_FDOT2
    return __builtin_amdgcn_fdot2(a, b, c, false);
#else
    return fmaf((float)a.y, (float)b.y, fmaf((float)a.x, (float)b.x, c));
#endif
}

// hot path: single-instruction pack (v_cvt_pkrtz_f16_f32)
__device__ __forceinline__ uint32_t pkz(float a, float b) {
    auto v = __builtin_amdgcn_cvt_pkrtz(a, b);
    return __builtin_bit_cast(uint32_t, v);
}
__device__ __forceinline__ f16x2 upk(uint32_t u) {
    return __builtin_bit_cast(f16x2, u);
}

// DPP add: x + x_from(lane permuted by ctrl); VALU pipe, no DS.
#define DPP_XOR1 0xB1    // quad_perm [1,0,3,2]
#define DPP_XOR2 0x4E    // quad_perm [2,3,0,1]
#define DPP_RHM  0x141   // row_half_mirror (xor-7 within 8-lane half-row)
template <int CTRL>
__device__ __forceinline__ float dpp_add(float x) {
    int v = __builtin_amdgcn_update_dpp(
        0, __builtin_bit_cast(int, x), CTRL, 0xF, 0xF, true);
    return x + __builtin_bit_cast(float, v);
}

#define Bn 2048
#define Dn 16
#define Hn 256
#define Tn 50
#define CH 20            // dwords per 32-k h chunk: 16 data + 4 pad

constexpr float T_LO = 1e-3f;
constexpr float DTc  = (1.0f - 1e-3f) / (float)(Tn - 1);
constexpr float W1W  = DTc * (1.f / 6.f);
constexpr float W2W  = DTc * (2.f / 6.f);

constexpr float nh_c(float t) { return -0.5f * (0.1f + 19.9f * t); }
constexpr float wbsum_c() {
    float s = 0.f;
    for (int j = 0; j < Tn - 1; ++j) {
        float t0 = T_LO + (float)j * DTc;
        float tm = t0 + 0.5f * DTc;
        float t1 = t0 + DTc;
        s += W1W * nh_c(t0) + 2.f * W2W * nh_c(tm) + W1W * nh_c(t1);
    }
    return s;
}
constexpr float WBSUM = wbsum_c();   // sum of RK-weighted (-beta/2) factors

__global__ __launch_bounds__(64) void ode_kernel(
    const float* __restrict__ x_in,   // [B][D]
    const float* __restrict__ W1,     // [D][H]
    const float* __restrict__ b1v,    // [H]
    const float* __restrict__ wtv,    // [H]
    const float* __restrict__ W2,     // [H][D]
    const float* __restrict__ b2v,    // [D]
    float* __restrict__ out)          // xf[B*D] | ldjf[B] | xt[T*B*D]
{
    __shared__ __align__(16) uint32_t h_lds[8 * CH];  // h, f16-pair packed

    const int L  = threadIdx.x;       // one wave per block = one sample
    const int g8 = L >> 3;            // i-pair group 0..7
    const int c  = L & 7;             // phase-2 k-chunk (32 k's)
    const int ia = 2 * g8, ib = ia + 1;
    const int k0 = 4 * L;             // phase-1: this lane's 4 hidden units
    const int gs = blockIdx.x;

    const float K2 = 2.88539008f;     // 2*log2(e): u' = K2*u, exp2(u') = e^{2u}

    // ---- one-time init: weights packed to f16 registers ----
    f16x2 w1p[4][8];                  // prescaled: {K2*W1[2j][k0+q], K2*W1[2j+1][k0+q]}
    float b1k[4], wtk[4], ck[4];
    #pragma unroll
    for (int q = 0; q < 4; ++q) {
        const int k = k0 + q;
        #pragma unroll
        for (int j = 0; j < 8; ++j) {
            f16x2 v;
            v.x = (_Float16)(K2 * W1[(2 * j)     * Hn + k]);
            v.y = (_Float16)(K2 * W1[(2 * j + 1) * Hn + k]);
            w1p[q][j] = v;
        }
        b1k[q] = K2 * b1v[k];
        wtk[q] = K2 * wtv[k];
        float s = 0.f;                // ck from ORIGINAL f32 weights
        #pragma unroll
        for (int ii = 0; ii < 16; ++ii)
            s = fmaf(W1[ii * Hn + k], W2[k * Dn + ii], s);
        ck[q] = s;
    }
    const float cksum = (ck[0] + ck[1]) + (ck[2] + ck[3]);

    f16x2 w2a[16], w2b[16];           // [m] = {W2[32c+2m][i*], W2[32c+2m+1][i*]}
    #pragma unroll
    for (int m = 0; m < 16; ++m) {
        f16x2 va, vb;
        va.x = (_Float16)W2[(32 * c + 2 * m)     * Dn + ia];
        va.y = (_Float16)W2[(32 * c + 2 * m + 1) * Dn + ia];
        vb.x = (_Float16)W2[(32 * c + 2 * m)     * Dn + ib];
        vb.y = (_Float16)W2[(32 * c + 2 * m + 1) * Dn + ib];
        w2a[m] = va; w2b[m] = vb;
    }
    const float b2a8 = 0.125f * b2v[ia];   // b2 / 8: folded into accumulator
    const float b2b8 = 0.125f * b2v[ib];   // init, restored by the 8-lane sum

    float xa = x_in[gs * Dn + ia];
    float xb = x_in[gs * Dn + ib];
    float ldjl = 0.f;                 // per-lane ldj partial (-sum wb*h^2ck)

    float* xf_out  = out;
    float* ldj_out = out + (size_t)Bn * Dn;
    float* xt_ptr  = out + (size_t)Bn * Dn + Bn + gs * Dn + ia;

    if (c == 0) *(float2*)xt_ptr = make_float2(xa, xb);   // xt[0]
    xt_ptr += Bn * Dn;

    const int hwidx = CH * (L >> 3) + 2 * (L & 7);        // h write slot (b64)

    // eval-point broadcast registers (uniform -> SGPRs)
    uint32_t se0, se1, se2, se3, se4, se5, se6, se7;
    auto bcast = [&](float ea, float eb) {
        const uint32_t vpk = pkz(ea, eb);     // every lane packs ITS pair
        se0 = __builtin_amdgcn_readlane(vpk,  0);
        se1 = __builtin_amdgcn_readlane(vpk,  8);
        se2 = __builtin_amdgcn_readlane(vpk, 16);
        se3 = __builtin_amdgcn_readlane(vpk, 24);
        se4 = __builtin_amdgcn_readlane(vpk, 32);
        se5 = __builtin_amdgcn_readlane(vpk, 40);
        se6 = __builtin_amdgcn_readlane(vpk, 48);
        se7 = __builtin_amdgcn_readlane(vpk, 56);
    };

    auto Feval = [&](float xeva, float xevb, const float (&ui)[4],
                     float nhb, float wb, float& dxa, float& dxb) {
        // ---- phase 1: this lane's 4 hidden units (SGPR-broadcast x) ----
        const f16x2 xp[8] = { upk(se0), upk(se1), upk(se2), upk(se3),
                              upk(se4), upk(se5), upk(se6), upk(se7) };
        float u0 = ui[0], u1 = ui[1], u2 = ui[2], u3 = ui[3];
        #pragma unroll
        for (int j = 0; j < 8; ++j) {
            u0 = fdot2f(xp[j], w1p[0][j], u0);
            u1 = fdot2f(xp[j], w1p[1][j], u1);
            u2 = fdot2f(xp[j], w1p[2][j], u2);
            u3 = fdot2f(xp[j], w1p[3][j], u3);
        }
        // u is prescaled: exp2(u) = e^{2u_true}. tanh = 1 - 2/(E+1);
        // E->inf => h=1, E->0 => h=-1: saturation correct, no clamp.
        const float h0 = fmaf(-2.f, __builtin_amdgcn_rcpf(__builtin_amdgcn_exp2f(u0) + 1.f), 1.f);
        const float h1 = fmaf(-2.f, __builtin_amdgcn_rcpf(__builtin_amdgcn_exp2f(u1) + 1.f), 1.f);
        const float h2 = fmaf(-2.f, __builtin_amdgcn_rcpf(__builtin_amdgcn_exp2f(u2) + 1.f), 1.f);
        const float h3 = fmaf(-2.f, __builtin_amdgcn_rcpf(__builtin_amdgcn_exp2f(u3) + 1.f), 1.f);
        *(uint2*)&h_lds[hwidx] = make_uint2(pkz(h0, h1), pkz(h2, h3));

        // trace partial: ldjl -= wb * sum(h^2 * ck); sum(ck) folded at end
        // (independent work inside the DS write->read bubble)
        const float q0 = h0 * h0, q1 = h1 * h1, q2 = h2 * h2, q3 = h3 * h3;
        const float sq = fmaf(q0, ck[0], fmaf(q1, ck[1], fmaf(q2, ck[2], q3 * ck[3])));
        ldjl = fmaf(-wb, sq, ldjl);

        asm volatile("" ::: "memory");     // keep h write above the reads

        // ---- phase 2: score for (ia, ib) over k-chunk c ----
        float sa0 = b2a8, sa1 = 0.f, sb0 = b2b8, sb1 = 0.f;
        #pragma unroll
        for (int mq = 0; mq < 4; ++mq) {
            const uint4 hv = *(const uint4*)&h_lds[CH * c + 4 * mq];
            const f16x2 p0 = upk(hv.x), p1 = upk(hv.y), p2 = upk(hv.z), p3 = upk(hv.w);
            sa0 = fdot2f(p0, w2a[4 * mq + 0], sa0);
            sb0 = fdot2f(p0, w2b[4 * mq + 0], sb0);
            sa1 = fdot2f(p1, w2a[4 * mq + 1], sa1);
            sb1 = fdot2f(p1, w2b[4 * mq + 1], sb1);
            sa0 = fdot2f(p2, w2a[4 * mq + 2], sa0);
            sb0 = fdot2f(p2, w2b[4 * mq + 2], sb0);
            sa1 = fdot2f(p3, w2a[4 * mq + 3], sa1);
            sb1 = fdot2f(p3, w2b[4 * mq + 3], sb1);
        }
        float sca = sa0 + sa1, scb = sb0 + sb1;
        // 8-lane reduce on the VALU pipe (DPP), no DS ops:
        sca = dpp_add<DPP_XOR1>(sca);  scb = dpp_add<DPP_XOR1>(scb);
        sca = dpp_add<DPP_XOR2>(sca);  scb = dpp_add<DPP_XOR2>(scb);
        sca = dpp_add<DPP_RHM >(sca);  scb = dpp_add<DPP_RHM >(scb);

        dxa = nhb * (xeva + sca);
        dxb = nhb * (xevb + scb);
    };

    // per-t-value uniforms, hoisted off the Feval critical path
    float ui0[4], uim[4], uit[4];
    #pragma unroll
    for (int q = 0; q < 4; ++q) ui0[q] = fmaf(T_LO, wtk[q], b1k[q]);
    float nhb0 = -0.5f * fmaf(T_LO, 19.9f, 0.1f);

    bcast(xa, xb);
    for (int j = 0; j < Tn - 1; ++j) {
        const float t0 = fmaf((float)j, DTc, T_LO);
        const float tm = t0 + 0.5f * DTc;
        const float t1 = t0 + DTc;
        #pragma unroll
        for (int q = 0; q < 4; ++q) {
            uim[q] = fmaf(tm, wtk[q], b1k[q]);
            uit[q] = fmaf(t1, wtk[q], b1k[q]);
        }
        const float nhbm = -0.5f * fmaf(tm, 19.9f, 0.1f);
        const float nhb1 = -0.5f * fmaf(t1, 19.9f, 0.1f);
        const float wb0 = W1W * nhb0;
        const float wbm = W2W * nhbm;      // shared by k2 and k3
        const float wb1 = W1W * nhb1;

        float k1a, k1b, k2a, k2b, k3a, k3b, k4a, k4b;

        Feval(xa, xb, ui0, nhb0, wb0, k1a, k1b);
        const float e2a = fmaf(0.5f * DTc, k1a, xa);
        const float e2b = fmaf(0.5f * DTc, k1b, xb);
        bcast(e2a, e2b);
        Feval(e2a, e2b, uim, nhbm, wbm, k2a, k2b);
        const float e3a = fmaf(0.5f * DTc, k2a, xa);
        const float e3b = fmaf(0.5f * DTc, k2b, xb);
        bcast(e3a, e3b);
        Feval(e3a, e3b, uim, nhbm, wbm, k3a, k3b);
        const float e4a = fmaf(DTc, k3a, xa);
        const float e4b = fmaf(DTc, k3b, xb);
        bcast(e4a, e4b);
        Feval(e4a, e4b, uit, nhb1, wb1, k4a, k4b);

        xa = fmaf(W1W, k1a + 2.f * (k2a + k3a) + k4a, xa);
        xb = fmaf(W1W, k1b + 2.f * (k2b + k3b) + k4b, xb);
        if (c == 0) *(float2*)xt_ptr = make_float2(xa, xb);
        xt_ptr += Bn * Dn;
        bcast(xa, xb);

        #pragma unroll
        for (int q = 0; q < 4; ++q) ui0[q] = uit[q];   // t1 -> next t0
        nhb0 = nhb1;
    }

    if (c == 0) *(float2*)(xf_out + gs * Dn + ia) = make_float2(xa, xb);

    // ldj: fold the constant (D/64 + sum ck) * sum(wb) term, then butterfly
    ldjl = fmaf(cksum + 0.25f, WBSUM, ldjl);
    #pragma unroll
    for (int off = 1; off < 64; off <<= 1)
        ldjl += __shfl_xor(ldjl, off);
    if (L == 0) ldj_out[gs] = ldjl;
}

extern "C" void kernel_launch(void* const* d_in, const int* in_sizes, int n_in,
                              void* d_out, int out_size, void* d_ws, size_t ws_size,
                              hipStream_t stream) {
    const float* x  = (const float*)d_in[0];
    const float* W1 = (const float*)d_in[1];
    const float* b1 = (const float*)d_in[2];
    const float* wt = (const float*)d_in[3];
    const float* W2 = (const float*)d_in[4];
    const float* b2 = (const float*)d_in[5];
    (void)in_sizes; (void)n_in; (void)out_size; (void)d_ws; (void)ws_size;
    ode_kernel<<<Bn, 64, 0, stream>>>(x, W1, b1, wt, W2, b2, (float*)d_out);
}